// Round 11
// baseline (111.745 us; speedup 1.0000x reference)
//
#include <hip/hip_runtime.h>
#include <hip/hip_bf16.h>
#include <math.h>

#define DIM 1024
#define HEADS 16
#define DH 64
#define WINDOW 32
#define TSEQ 2048
#define BB 2
#define ROWS (BB * TSEQ)      // 4096
#define NQKV (3 * DIM)        // 3072

typedef __bf16 bf16x8 __attribute__((ext_vector_type(8)));
typedef unsigned short u16x8 __attribute__((ext_vector_type(8)));
typedef float f32x4 __attribute__((ext_vector_type(4)));

__device__ __forceinline__ unsigned short f2bf(float f) {
  unsigned int u = __float_as_uint(f);
  u += 0x7fffu + ((u >> 16) & 1u);   // round-to-nearest-even
  return (unsigned short)(u >> 16);
}

__device__ __forceinline__ void glds16(const void* g, void* l) {
  __builtin_amdgcn_global_load_lds((const __attribute__((address_space(1))) void*)g,
                                   (__attribute__((address_space(3))) void*)l,
                                   16, 0, 0);
}

// ---------------- fused prep: weight cvt (wqkv, wout) + RoPE tables ----------------
__global__ __launch_bounds__(256) void prep_kernel(
    const float* __restrict__ wqkv, const float* __restrict__ wout,
    unsigned short* __restrict__ wqb, unsigned short* __restrict__ wob,
    float* __restrict__ ctab, float* __restrict__ stab) {
  int bid = blockIdx.x;
  if (bid < 4096) {
    const float* in = (bid < 3072) ? wqkv : wout;
    unsigned short* outp = (bid < 3072) ? wqb : wob;
    int i = (bid < 3072 ? bid : bid - 3072) * 256 + threadIdx.x;
    float4 v = *(const float4*)&in[(size_t)i * 4];
    ushort4 o = make_ushort4(f2bf(v.x), f2bf(v.y), f2bf(v.z), f2bf(v.w));
    *(ushort4*)&outp[(size_t)i * 4] = o;
  } else {
    int idx = (bid - 4096) * 256 + threadIdx.x;  // 2048*32
    int t = idx >> 5, i = idx & 31;
    float inv = powf(10000.0f, -(float)i / 32.0f);
    float f = (float)t * inv;
    float sv, cv;
    sincosf(f, &sv, &cv);
    ctab[idx] = cv;
    stab[idx] = sv;
  }
}

// ---------------- LayerNorm -> bf16 ----------------
__global__ __launch_bounds__(256) void ln_kernel(
    const float* __restrict__ x, const float* __restrict__ lw,
    const float* __restrict__ lb, unsigned short* __restrict__ xn) {
  const int row = blockIdx.x;
  const int c = threadIdx.x * 4;
  const float4 v = *(const float4*)&x[(size_t)row * DIM + c];
  float s = v.x + v.y + v.z + v.w;
  float s2 = v.x * v.x + v.y * v.y + v.z * v.z + v.w * v.w;
#pragma unroll
  for (int m = 32; m; m >>= 1) {
    s += __shfl_xor(s, m);
    s2 += __shfl_xor(s2, m);
  }
  __shared__ float ps[4], ps2[4];
  if ((threadIdx.x & 63) == 0) {
    ps[threadIdx.x >> 6] = s;
    ps2[threadIdx.x >> 6] = s2;
  }
  __syncthreads();
  s = ps[0] + ps[1] + ps[2] + ps[3];
  s2 = ps2[0] + ps2[1] + ps2[2] + ps2[3];
  const float mu = s * (1.0f / DIM);
  const float rs = rsqrtf(s2 * (1.0f / DIM) - mu * mu + 1e-5f);
  const float4 wv = *(const float4*)&lw[c];
  const float4 bv = *(const float4*)&lb[c];
  ushort4 o = make_ushort4(f2bf((v.x - mu) * rs * wv.x + bv.x),
                           f2bf((v.y - mu) * rs * wv.y + bv.y),
                           f2bf((v.z - mu) * rs * wv.z + bv.z),
                           f2bf((v.w - mu) * rs * wv.w + bv.w));
  *(ushort4*)&xn[(size_t)row * DIM + c] = o;
}

// ================= QKV GEMM: 256x256 tile, 8-wave, 8-phase pipeline =================
// C[4096,3072] = A[4096,1024] * B[3072,1024]^T, fused RoPE epilogue (bf16 out).
// Template per guide §5: BK=64, 2 LDS buffers (1 K-tile each, quadrant-split
// half-tiles), JIT staging 4 phases ahead, counted vmcnt(4) (never 0 in loop),
// setprio around MFMA, XOR bank-swizzle applied on BOTH source col and read col.
// All LDS buffer indices are compile-time literals (macro-unrolled).
#define QKV_K 1024
#define QKV_N 3072

// stage half-tile macros: tile NT -> buffer NB (literals)
#define SA(NB, NT, Q) do { \
    glds16(A + (size_t)(bm + 0 * 128 + (Q) * 64 + srow) * QKV_K + (NT) * 64 + scolw, \
           &AQ[NB][Q][0 * 4096 + ldst]); \
    glds16(A + (size_t)(bm + 1 * 128 + (Q) * 64 + srow) * QKV_K + (NT) * 64 + scolw, \
           &AQ[NB][Q][1 * 4096 + ldst]); \
  } while (0)
#define SB(NB, NT, Q) do { \
    glds16(B + (size_t)(bn + (0 * 2 + (t >> 8)) * 64 + (Q) * 32 + ((t >> 3) & 31)) * QKV_K + (NT) * 64 + scolw, \
           &BQ[NB][Q][0 * 4096 + ldst]); \
    glds16(B + (size_t)(bn + (1 * 2 + (t >> 8)) * 64 + (Q) * 32 + ((t >> 3) & 31)) * QKV_K + (NT) * 64 + scolw, \
           &BQ[NB][Q][1 * 4096 + ldst]); \
  } while (0)

#define VM4 asm volatile("s_waitcnt vmcnt(4)" ::: "memory")
#define VM0 asm volatile("s_waitcnt vmcnt(0)" ::: "memory")
#define VMNONE do {} while (0)
#define SNONE do {} while (0)

// one phase: ds_read quadrant frags; issue stage; barrier; lgkm drain; MFMA x16;
// counted-vmcnt; barrier.
#define PHASE(NB, QM, QN, STG, VMW) do { \
    bf16x8 af[4][2], bq[2][2]; \
    _Pragma("unroll") \
    for (int mi = 0; mi < 4; ++mi) { \
      const int ra = wm * 64 + mi * 16 + fr; \
      const int cx = ((ra >> 2) & 1) << 4; \
      af[mi][0] = *(const bf16x8*)&AQ[NB][QM][ra * 64 + (fko ^ cx)]; \
      af[mi][1] = *(const bf16x8*)&AQ[NB][QM][ra * 64 + 32 + (fko ^ cx)]; \
    } \
    _Pragma("unroll") \
    for (int nj = 0; nj < 2; ++nj) { \
      const int rb = wn * 32 + nj * 16 + fr; \
      const int cx = ((rb >> 2) & 1) << 4; \
      bq[nj][0] = *(const bf16x8*)&BQ[NB][QN][rb * 64 + (fko ^ cx)]; \
      bq[nj][1] = *(const bf16x8*)&BQ[NB][QN][rb * 64 + 32 + (fko ^ cx)]; \
    } \
    STG; \
    __builtin_amdgcn_s_barrier(); \
    asm volatile("s_waitcnt lgkmcnt(0)" ::: "memory"); \
    __builtin_amdgcn_sched_barrier(0); \
    __builtin_amdgcn_s_setprio(1); \
    _Pragma("unroll") \
    for (int ks = 0; ks < 2; ++ks) \
      _Pragma("unroll") \
      for (int mi = 0; mi < 4; ++mi) \
        _Pragma("unroll") \
        for (int nj = 0; nj < 2; ++nj) \
          acc[(QM) * 4 + mi][(QN) * 2 + nj] = __builtin_amdgcn_mfma_f32_16x16x32_bf16( \
              af[mi][ks], bq[nj][ks], acc[(QM) * 4 + mi][(QN) * 2 + nj], 0, 0, 0); \
    __builtin_amdgcn_s_setprio(0); \
    VMW; \
    __builtin_amdgcn_s_barrier(); \
  } while (0)

// one K-tile (reads buf NB) staging next tile NT1 into buf NBX.
// stage order {A0,B0,B1,A1}; vmcnt(4) at phase ends 1,2,4 (derived-safe:
// outstanding oscillates 4..8 loads; each phase's inputs proven landed).
#define TILE(NB, NBX, NT1) do { \
    PHASE(NB, 0, 0, SA(NBX, NT1, 0), VM4); \
    PHASE(NB, 0, 1, SB(NBX, NT1, 0), VM4); \
    PHASE(NB, 1, 0, SB(NBX, NT1, 1), VMNONE); \
    PHASE(NB, 1, 1, SA(NBX, NT1, 1), VM4); \
  } while (0)

__global__ __launch_bounds__(512, 2) void gemm_qkv8(
    const unsigned short* __restrict__ A, const unsigned short* __restrict__ B,
    unsigned short* __restrict__ Cb,
    const float* __restrict__ ctab, const float* __restrict__ stab) {
  // half-tiles: AQ[buf][qm] = rows {wm*128 + qm*64 + 0..63} as [wm*64+r][64] u16
  //             BQ[buf][qn] = rows {wn*64 + qn*32 + 0..31} as [wn*32+r][64] u16
  __shared__ unsigned short AQ[2][2][8192];   // 64 KiB
  __shared__ unsigned short BQ[2][2][8192];   // 64 KiB
  const int t = threadIdx.x;
  const int lane = t & 63;
  const int wave = t >> 6;      // 0..7
  const int wm = wave >> 2;     // 0..1 (row half)
  const int wn = wave & 3;      // 0..3 (col quarter)
  const int bm = blockIdx.y * 256;
  const int bn = blockIdx.x * 256;
  const int fr = lane & 15;
  const int fko = (lane >> 4) * 8;

  f32x4 acc[8][4] = {};

  // staging thread-constants: linear LDS dest (t*8 u16), pre-swizzled source col
  const int srow = t >> 3;                                   // 0..63
  const int scolw = ((t & 7) * 8) ^ (((t >> 5) & 1) << 4);   // col ^ f(row)
  const int ldst = (t & ~63) * 8;                            // wave-uniform base

  // ---- prologue: stage tile 0 into buf 0, order {A0,B0,B1,A1} ----
  SA(0, 0, 0); SB(0, 0, 0); SB(0, 0, 1); SA(0, 0, 1);
  VM4;                                  // A0,B0 landed (B1,A1 may fly)
  __builtin_amdgcn_s_barrier();

  // ---- main loop: 16 K-tiles, buffers alternate via literal indices ----
  for (int tt = 0; tt < 14; tt += 2) {
    TILE(0, 1, tt + 1);
    TILE(1, 0, tt + 2);
  }
  TILE(0, 1, 15);
  // final tile 15 (buf 1): no staging; drain rest after phase 1
  PHASE(1, 0, 0, SNONE, VM0);
  PHASE(1, 0, 1, SNONE, VMNONE);
  PHASE(1, 1, 0, SNONE, VMNONE);
  PHASE(1, 1, 1, SNONE, VMNONE);

  // ---- epilogue: fused RoPE (q,k) + 1/8 q-scale, bf16 store ----
  const int cr = (lane >> 4) * 4;
  const int cc = lane & 15;
  const int ctype = bn >> 10;  // 0=q, 1=k, 2=v (256-col tile never straddles)
#pragma unroll
  for (int m = 0; m < 8; ++m) {
#pragma unroll
    for (int rr = 0; rr < 4; ++rr) {
      const int row = bm + wm * 128 + m * 16 + cr + rr;
      const int pos = row & (TSEQ - 1);
      if (ctype == 2) {
#pragma unroll
        for (int n = 0; n < 4; ++n) {
          const int col = bn + wn * 64 + n * 16 + cc;
          Cb[(size_t)row * QKV_N + col] = f2bf(acc[m][n][rr]);
        }
      } else {
#pragma unroll
        for (int n = 0; n < 2; ++n) {
          const int col = bn + wn * 64 + n * 16 + cc;
          const float cv = ctab[pos * 32 + n * 16 + cc];
          const float sv = stab[pos * 32 + n * 16 + cc];
          float lo = acc[m][n][rr], hi = acc[m][n + 2][rr];
          float olo = lo * cv - hi * sv;
          float ohi = hi * cv + lo * sv;
          if (ctype == 0) { olo *= 0.125f; ohi *= 0.125f; }
          Cb[(size_t)row * QKV_N + col] = f2bf(olo);
          Cb[(size_t)row * QKV_N + col + 32] = f2bf(ohi);
        }
      }
    }
  }
}

// ---------------- proj GEMM: exact round-7 kernel (known-good) ----------------
// C[M,N] = A[M,K]*B[N,K]^T + resid, fp32 out. 128x128 tile, BK=32, 2-barrier.
__global__ __launch_bounds__(256) void gemm_proj(
    const unsigned short* __restrict__ A, const unsigned short* __restrict__ B,
    float* __restrict__ Cf, const float* __restrict__ resid, int M, int N, int K) {
  __shared__ unsigned short Al[128 * 32];
  __shared__ unsigned short Bl[128 * 32];
  const int t = threadIdx.x;
  const int lane = t & 63;
  const int wave = t >> 6;
  const int wm = wave >> 1;
  const int wn = wave & 1;
  const int bm = blockIdx.y * 128;
  const int bn = blockIdx.x * 128;

  f32x4 acc[4][4] = {};

  const int srow = t >> 2;
  const int scol = (t & 3) * 8;
  const unsigned short* ga = A + (size_t)(bm + srow) * K + scol;
  const unsigned short* gb = B + (size_t)(bn + srow) * K + scol;
  unsigned short* la = Al + (t & ~63) * 8;
  unsigned short* lb = Bl + (t & ~63) * 8;

  const int fr = lane & 15;
  const int fko = (lane >> 4) * 8;

  for (int k0 = 0; k0 < K; k0 += 32) {
    __syncthreads();
    glds16(ga + k0, la);
    glds16(ga + (size_t)64 * K + k0, la + 64 * 32);
    glds16(gb + k0, lb);
    glds16(gb + (size_t)64 * K + k0, lb + 64 * 32);
    __syncthreads();
    bf16x8 af[4], bfr[4];
#pragma unroll
    for (int i = 0; i < 4; ++i)
      af[i] = *(const bf16x8*)&Al[(wm * 64 + i * 16 + fr) * 32 + fko];
#pragma unroll
    for (int j = 0; j < 4; ++j)
      bfr[j] = *(const bf16x8*)&Bl[(wn * 64 + j * 16 + fr) * 32 + fko];
#pragma unroll
    for (int i = 0; i < 4; ++i)
#pragma unroll
      for (int j = 0; j < 4; ++j)
        acc[i][j] = __builtin_amdgcn_mfma_f32_16x16x32_bf16(af[i], bfr[j], acc[i][j], 0, 0, 0);
  }

  const int cr = (lane >> 4) * 4;
  const int cc = lane & 15;
#pragma unroll
  for (int i = 0; i < 4; ++i)
#pragma unroll
    for (int j = 0; j < 4; ++j)
#pragma unroll
      for (int r = 0; r < 4; ++r) {
        int row = bm + wm * 64 + i * 16 + cr + r;
        int col = bn + wn * 64 + j * 16 + cc;
        size_t idx = (size_t)row * N + col;
        Cf[idx] = acc[i][j][r] + resid[idx];
      }
}

// ---------------- sliding-window attention, MFMA (unchanged, passing) ----------------
#define KST 72
#define VST 104
#define PST 72
__global__ __launch_bounds__(256) void attn_kernel(const unsigned short* __restrict__ qkv,
                                                   unsigned short* __restrict__ out) {
  __shared__ unsigned short Kb[96 * KST];
  __shared__ unsigned short Vt[64 * VST];
  __shared__ unsigned short Pl[64 * PST];
  const int qtile = blockIdx.x;
  const int bh = blockIdx.y;
  const int b = bh >> 4, h = bh & 15;
  const int qs = qtile * 64;
  const int t = threadIdx.x;

  for (int e = t; e < 768; e += 256) {
    int r = e >> 3, seg = e & 7;
    int j = qs - 32 + r;
    u16x8 kv = {};
    if (j >= 0)
      kv = *(const u16x8*)&qkv[((size_t)(b * TSEQ + j)) * NQKV + DIM + h * 64 + seg * 8];
    *(u16x8*)&Kb[r * KST + seg * 8] = kv;
  }
  for (int e = t; e < 768; e += 256) {
    int r = e >> 3, seg = e & 7;
    int j = qs - 32 + r;
    u16x8 vv = {};
    if (j >= 0)
      vv = *(const u16x8*)&qkv[((size_t)(b * TSEQ + j)) * NQKV + 2 * DIM + h * 64 + seg * 8];
#pragma unroll
    for (int u = 0; u < 8; ++u) Vt[(seg * 8 + u) * VST + r] = vv[u];
  }
  for (int e = t; e < 64 * PST / 8; e += 256)
    *(u16x8*)&Pl[e * 8] = (u16x8){};
  __syncthreads();

  const int wave = t >> 6;
  const int lane = t & 63;
  const int fr = lane & 15;
  const int fko = (lane >> 4) * 8;
  const int g = lane >> 4;
  const int cc = lane & 15;
  const int kmin = 32 - qs - wave * 16;

  const unsigned short* qrow = qkv + ((size_t)(b * TSEQ + qs + wave * 16 + fr)) * NQKV + h * 64;
  bf16x8 qf0 = *(const bf16x8*)&qrow[fko];
  bf16x8 qf1 = *(const bf16x8*)&qrow[32 + fko];

  f32x4 sc[3] = {};
#pragma unroll
  for (int kt = 0; kt < 3; ++kt) {
    const unsigned short* kb = &Kb[(wave * 16 + kt * 16 + fr) * KST];
    bf16x8 kf0 = *(const bf16x8*)&kb[fko];
    bf16x8 kf1 = *(const bf16x8*)&kb[32 + fko];
    sc[kt] = __builtin_amdgcn_mfma_f32_16x16x32_bf16(qf0, kf0, sc[kt], 0, 0, 0);
    sc[kt] = __builtin_amdgcn_mfma_f32_16x16x32_bf16(qf1, kf1, sc[kt], 0, 0, 0);
  }

#pragma unroll
  for (int reg = 0; reg < 4; ++reg) {
    const int r = g * 4 + reg;
    float sv[3];
    bool va[3];
    float mx = -1e30f;
#pragma unroll
    for (int kt = 0; kt < 3; ++kt) {
      int kk = kt * 16 + cc;
      bool valid = (kk >= r + 1) && (kk <= r + 32) && (kk >= kmin);
      va[kt] = valid;
      sv[kt] = valid ? sc[kt][reg] : -1e30f;
      mx = fmaxf(mx, sv[kt]);
    }
#pragma unroll
    for (int mm = 8; mm; mm >>= 1) mx = fmaxf(mx, __shfl_xor(mx, mm));
    float pe[3], sum = 0.f;
#pragma unroll
    for (int kt = 0; kt < 3; ++kt) {
      pe[kt] = va[kt] ? __expf(sv[kt] - mx) : 0.f;
      sum += pe[kt];
    }
#pragma unroll
    for (int mm = 8; mm; mm >>= 1) sum += __shfl_xor(sum, mm);
    float rinv = 1.0f / sum;
#pragma unroll
    for (int kt = 0; kt < 3; ++kt)
      Pl[(wave * 16 + r) * PST + kt * 16 + cc] = f2bf(pe[kt] * rinv);
  }

  const unsigned short* prow = &Pl[(wave * 16 + fr) * PST];
  bf16x8 pf0 = *(const bf16x8*)&prow[fko];
  bf16x8 pf1 = *(const bf16x8*)&prow[32 + fko];
  f32x4 o[4] = {};
#pragma unroll
  for (int nt = 0; nt < 4; ++nt) {
    const unsigned short* vrow = &Vt[(nt * 16 + fr) * VST + wave * 16];
    bf16x8 vf0 = *(const bf16x8*)&vrow[fko];
    bf16x8 vf1 = *(const bf16x8*)&vrow[32 + fko];
    o[nt] = __builtin_amdgcn_mfma_f32_16x16x32_bf16(pf0, vf0, o[nt], 0, 0, 0);
    o[nt] = __builtin_amdgcn_mfma_f32_16x16x32_bf16(pf1, vf1, o[nt], 0, 0, 0);
  }

#pragma unroll
  for (int nt = 0; nt < 4; ++nt)
#pragma unroll
    for (int reg = 0; reg < 4; ++reg) {
      int qg = qs + wave * 16 + g * 4 + reg;
      out[((size_t)(b * TSEQ + qg)) * DIM + h * 64 + nt * 16 + cc] = f2bf(o[nt][reg]);
    }
}

extern "C" void kernel_launch(void* const* d_in, const int* in_sizes, int n_in,
                              void* d_out, int out_size, void* d_ws, size_t ws_size,
                              hipStream_t stream) {
  const float* x    = (const float*)d_in[0];
  const float* lw   = (const float*)d_in[1];
  const float* lbp  = (const float*)d_in[2];
  const float* wqkv = (const float*)d_in[3];
  const float* wout = (const float*)d_in[4];
  float* out = (float*)d_out;

  char* w = (char*)d_ws;
  unsigned short* xn   = (unsigned short*)(w);              //  8 MiB [4096][1024]
  unsigned short* wqb  = (unsigned short*)(w + 8388608);    //  6 MiB [3072][1024]
  unsigned short* wob  = (unsigned short*)(w + 14680064);   //  2 MiB [1024][1024]
  unsigned short* atb  = (unsigned short*)(w + 16777216);   //  8 MiB [4096][1024]
  float* ctab = (float*)(w + 25165824);                     // 256 KiB
  float* stab = (float*)(w + 25427968);                     // 256 KiB
  unsigned short* qkvb = (unsigned short*)(w + 25690112);   // 24 MiB [4096][3072]

  prep_kernel<<<4352, 256, 0, stream>>>(wqkv, wout, wqb, wob, ctab, stab);
  ln_kernel<<<ROWS, 256, 0, stream>>>(x, lw, lbp, xn);
  gemm_qkv8<<<dim3(12, 16), 512, 0, stream>>>(xn, wqb, qkvb, ctab, stab);
  attn_kernel<<<dim3(32, 32), 256, 0, stream>>>(qkvb, atb);
  gemm_proj<<<dim3(8, 32), 256, 0, stream>>>(atb, wob, out, x, ROWS, DIM, DIM);
}